// Round 3
// baseline (18102.710 us; speedup 1.0000x reference)
//
#include <hip/hip_runtime.h>
#include <math.h>

#define N_NODES   50000
#define N_EDGES   800000
#define IN_DIM    128
#define HIDDEN    256
#define N_ETYPES  13
#define N_STEPS   6
#define NUM_GRAPHS 64
#define NKEYS     (N_ETYPES * N_NODES)
#define SCAN_T    512

// ---------------- init h0 = [feat | zeros] ----------------
__global__ __launch_bounds__(256) void k_init_h(const float* __restrict__ feat,
                                                float* __restrict__ h) {
    int i = blockIdx.x * 256 + threadIdx.x;          // float4 index over N*64
    if (i >= N_NODES * 64) return;
    int v = i >> 6;
    int q = i & 63;
    float4 val;
    if (q < 32) val = ((const float4*)(feat + (size_t)v * IN_DIM))[q];
    else        val = make_float4(0.f, 0.f, 0.f, 0.f);
    ((float4*)(h + (size_t)v * HIDDEN))[q] = val;
}

// ---------------- CSR build: histogram / scan / place ----------------
__global__ __launch_bounds__(256) void k_hist(const int* __restrict__ dst,
                                              const int* __restrict__ et,
                                              int* __restrict__ counts) {
    int e = blockIdx.x * 256 + threadIdx.x;
    if (e >= N_EDGES) return;
    int key = et[e] * N_NODES + dst[e];
    atomicAdd(&counts[key], 1);
}

__global__ __launch_bounds__(SCAN_T) void k_scan1(const int* __restrict__ in,
                                                  int* __restrict__ lexcl,
                                                  int* __restrict__ bsums, int n) {
    __shared__ int s[SCAN_T];
    int i = blockIdx.x * SCAN_T + threadIdx.x;
    int v = (i < n) ? in[i] : 0;
    s[threadIdx.x] = v;
    __syncthreads();
    for (int off = 1; off < SCAN_T; off <<= 1) {
        int t = (threadIdx.x >= off) ? s[threadIdx.x - off] : 0;
        __syncthreads();
        s[threadIdx.x] += t;
        __syncthreads();
    }
    if (i < n) lexcl[i] = s[threadIdx.x] - v;
    if (threadIdx.x == SCAN_T - 1) bsums[blockIdx.x] = s[SCAN_T - 1];
}

__global__ __launch_bounds__(256) void k_scan2(int* __restrict__ bsums, int nb,
                                               int* __restrict__ ptr) {
    __shared__ int s[256];
    int tid = threadIdx.x;
    const int C = (nb + 255) / 256;                  // <= 8
    int vals[8];
    int base = tid * C;
    int sum = 0;
    for (int i = 0; i < C; ++i) {
        int idx = base + i;
        int v = (idx < nb) ? bsums[idx] : 0;
        vals[i] = sum;
        sum += v;
    }
    s[tid] = sum;
    __syncthreads();
    int own = sum;
    for (int off = 1; off < 256; off <<= 1) {
        int t = (tid >= off) ? s[tid - off] : 0;
        __syncthreads();
        s[tid] += t;
        __syncthreads();
    }
    int exclBlk = s[tid] - own;
    for (int i = 0; i < C; ++i) {
        int idx = base + i;
        if (idx < nb) bsums[idx] = exclBlk + vals[i];
    }
    if (tid == 0) ptr[NKEYS] = N_EDGES;              // end sentinel
}

__global__ __launch_bounds__(SCAN_T) void k_scan3(const int* __restrict__ lexcl,
                                                  const int* __restrict__ bsums,
                                                  int* __restrict__ ptr, int n) {
    int i = blockIdx.x * SCAN_T + threadIdx.x;
    if (i < n) ptr[i] = lexcl[i] + bsums[blockIdx.x];
}

// ebuf[pos] = SRC NODE of the edge (we never need the edge id itself) —
// saves one dependent random load in the hot gather loop.
__global__ __launch_bounds__(256) void k_place(const int* __restrict__ dst,
                                               const int* __restrict__ et,
                                               const int* __restrict__ src,
                                               int* __restrict__ cursor,
                                               int* __restrict__ ebuf) {
    int e = blockIdx.x * 256 + threadIdx.x;
    if (e >= N_EDGES) return;
    int key = et[e] * N_NODES + dst[e];
    int pos = atomicAdd(&cursor[key], 1);
    ebuf[pos] = src[e];
}

// ---------------- fused message kernel (BN = 256: gather once per step) ----
// Block = 64-node row tile, all 256 output columns.
//   a_tile = sum_t ( gather_sum_{etype t}(h) ) @ W[t]
// LDS: Sh[64][256] (64 KB, unpadded -> 2 blocks/CU) + Bs[16][256] (16 KB).
// Thread (tid): rows tr..tr+3 (tr=(tid>>4)*4), cols c0+64j (c0=(tid&15)*4,
// j=0..3) -> B ds_read_b128 at 16-float lane stride = 2-way bank alias (free).
__global__ __launch_bounds__(256, 2) void k_msg(const int* __restrict__ ebuf,
                                                const int* __restrict__ ptr,
                                                const float* __restrict__ h,
                                                const float* __restrict__ W,
                                                float* __restrict__ a) {
    __shared__ float Sh[64][256];
    __shared__ float Bs[16][256];
    const int br   = blockIdx.x * 64;
    const int tid  = threadIdx.x;
    const int lane = tid & 63;
    const int wave = tid >> 6;
    const int tr   = (tid >> 4) << 2;                // acc rows tr..tr+3
    const int c0   = (tid & 15) << 2;                // acc cols c0 + 64*j
    float4 acc[4][4] = {};                           // [row i][j]

    for (int t = 0; t < N_ETYPES; ++t) {
        // ---- gather S_t rows into Sh (one wave per row, lane covers 4 floats)
        const int* pT = ptr + (size_t)t * N_NODES;
        for (int r = wave; r < 64; r += 4) {
            int node = br + r;
            float4 s4 = make_float4(0.f, 0.f, 0.f, 0.f);
            if (node < N_NODES) {
                int beg = pT[node], end = pT[node + 1];
                for (int i = beg; i < end; ++i) {
                    int s = ebuf[i];                 // src node id
                    float4 v = ((const float4*)h)[(size_t)s * 64 + lane];
                    s4.x += v.x; s4.y += v.y; s4.z += v.z; s4.w += v.w;
                }
            }
            int c = lane << 2;
            Sh[r][c + 0] = s4.x; Sh[r][c + 1] = s4.y;
            Sh[r][c + 2] = s4.z; Sh[r][c + 3] = s4.w;
        }
        __syncthreads();
        // ---- GEMM: acc += Sh @ W[t]
        const float* Wt = W + (size_t)t * HIDDEN * HIDDEN;
        for (int k0 = 0; k0 < 256; k0 += 16) {
            const int krow = tid >> 4;               // 0..15
            #pragma unroll
            for (int j = 0; j < 4; ++j) {
                float4 bv = *(const float4*)(Wt + (size_t)(k0 + krow) * 256 + c0 + 64 * j);
                *(float4*)&Bs[krow][c0 + 64 * j] = bv;
            }
            __syncthreads();
            #pragma unroll
            for (int k = 0; k < 16; ++k) {
                float a0 = Sh[tr + 0][k0 + k];
                float a1 = Sh[tr + 1][k0 + k];
                float a2 = Sh[tr + 2][k0 + k];
                float a3 = Sh[tr + 3][k0 + k];
                #pragma unroll
                for (int j = 0; j < 4; ++j) {
                    float4 b = *(const float4*)&Bs[k][c0 + 64 * j];
                    acc[0][j].x += a0 * b.x; acc[0][j].y += a0 * b.y;
                    acc[0][j].z += a0 * b.z; acc[0][j].w += a0 * b.w;
                    acc[1][j].x += a1 * b.x; acc[1][j].y += a1 * b.y;
                    acc[1][j].z += a1 * b.z; acc[1][j].w += a1 * b.w;
                    acc[2][j].x += a2 * b.x; acc[2][j].y += a2 * b.y;
                    acc[2][j].z += a2 * b.z; acc[2][j].w += a2 * b.w;
                    acc[3][j].x += a3 * b.x; acc[3][j].y += a3 * b.y;
                    acc[3][j].z += a3 * b.z; acc[3][j].w += a3 * b.w;
                }
            }
            __syncthreads();
        }
    }
    #pragma unroll
    for (int i = 0; i < 4; ++i) {
        int row = br + tr + i;
        if (row < N_NODES) {
            #pragma unroll
            for (int j = 0; j < 4; ++j)
                *(float4*)(a + (size_t)row * 256 + c0 + 64 * j) = acc[i][j];
        }
    }
}

// ---------------- fused GRU kernel ----------------
// Per 64-row x 64-col tile: 6 register GEMM tiles (xr,xz,xn from a@W_ih^T,
// hr,hz,hn from h@W_hh^T), then gates in the epilogue.
__device__ __forceinline__ float sigm(float x) { return 1.0f / (1.0f + expf(-x)); }

#define FMA4T(ACC, S0, S1, S2, S3, B) \
    ACC[0][0] += S0 * B.x; ACC[0][1] += S0 * B.y; ACC[0][2] += S0 * B.z; ACC[0][3] += S0 * B.w; \
    ACC[1][0] += S1 * B.x; ACC[1][1] += S1 * B.y; ACC[1][2] += S1 * B.z; ACC[1][3] += S1 * B.w; \
    ACC[2][0] += S2 * B.x; ACC[2][1] += S2 * B.y; ACC[2][2] += S2 * B.z; ACC[2][3] += S2 * B.w; \
    ACC[3][0] += S3 * B.x; ACC[3][1] += S3 * B.y; ACC[3][2] += S3 * B.z; ACC[3][3] += S3 * B.w;

__global__ __launch_bounds__(256, 2) void k_gru(const float* __restrict__ a,
                                                const float* __restrict__ h,
                                                const float* __restrict__ W_ih,
                                                const float* __restrict__ W_hh,
                                                const float* __restrict__ b_ih,
                                                const float* __restrict__ b_hh,
                                                float* __restrict__ hN) {
    __shared__ float Aa[16][64];                     // a tile, [k][row]
    __shared__ float Ah[16][64];                     // h tile
    __shared__ float Bs[6][16][64];                  // W tiles [k][col]
    const int br  = blockIdx.x * 64;
    const int f0  = blockIdx.y * 64;                 // column within gate slice
    const int tid = threadIdx.x;
    const int tr  = (tid >> 4) << 2;
    const int tc4 = (tid & 15) << 2;
    float axr[4][4] = {}, axz[4][4] = {}, axn[4][4] = {};
    float ahr[4][4] = {}, ahz[4][4] = {}, ahn[4][4] = {};

    const int arow = tid >> 2;                       // 0..63
    const int akq  = (tid & 3) << 2;                 // 0,4,8,12
    int aR = br + arow;
    if (aR >= N_NODES) aR = N_NODES - 1;             // clamp, stores guarded
    const int bc   = tid >> 2;                       // weight col 0..63
    const int bkq  = (tid & 3) << 2;

    for (int k0 = 0; k0 < 256; k0 += 16) {
        float4 av = *(const float4*)(a + (size_t)aR * 256 + k0 + akq);
        Aa[akq + 0][arow] = av.x; Aa[akq + 1][arow] = av.y;
        Aa[akq + 2][arow] = av.z; Aa[akq + 3][arow] = av.w;
        float4 hv = *(const float4*)(h + (size_t)aR * 256 + k0 + akq);
        Ah[akq + 0][arow] = hv.x; Ah[akq + 1][arow] = hv.y;
        Ah[akq + 2][arow] = hv.z; Ah[akq + 3][arow] = hv.w;
        #pragma unroll
        for (int g = 0; g < 3; ++g) {
            float4 wv = *(const float4*)(W_ih + (size_t)(g * 256 + f0 + bc) * 256 + k0 + bkq);
            Bs[g][bkq + 0][bc] = wv.x; Bs[g][bkq + 1][bc] = wv.y;
            Bs[g][bkq + 2][bc] = wv.z; Bs[g][bkq + 3][bc] = wv.w;
            float4 wh = *(const float4*)(W_hh + (size_t)(g * 256 + f0 + bc) * 256 + k0 + bkq);
            Bs[3 + g][bkq + 0][bc] = wh.x; Bs[3 + g][bkq + 1][bc] = wh.y;
            Bs[3 + g][bkq + 2][bc] = wh.z; Bs[3 + g][bkq + 3][bc] = wh.w;
        }
        __syncthreads();
        #pragma unroll
        for (int k = 0; k < 16; ++k) {
            float a0 = Aa[k][tr + 0], a1 = Aa[k][tr + 1], a2 = Aa[k][tr + 2], a3 = Aa[k][tr + 3];
            float h0 = Ah[k][tr + 0], h1 = Ah[k][tr + 1], h2 = Ah[k][tr + 2], h3 = Ah[k][tr + 3];
            float4 bxr = *(const float4*)&Bs[0][k][tc4];
            float4 bxz = *(const float4*)&Bs[1][k][tc4];
            float4 bxn = *(const float4*)&Bs[2][k][tc4];
            float4 bhr = *(const float4*)&Bs[3][k][tc4];
            float4 bhz = *(const float4*)&Bs[4][k][tc4];
            float4 bhn = *(const float4*)&Bs[5][k][tc4];
            FMA4T(axr, a0, a1, a2, a3, bxr)
            FMA4T(axz, a0, a1, a2, a3, bxz)
            FMA4T(axn, a0, a1, a2, a3, bxn)
            FMA4T(ahr, h0, h1, h2, h3, bhr)
            FMA4T(ahz, h0, h1, h2, h3, bhz)
            FMA4T(ahn, h0, h1, h2, h3, bhn)
        }
        __syncthreads();
    }

    const float4 bir  = *(const float4*)(b_ih + f0 + tc4);
    const float4 biz  = *(const float4*)(b_ih + 256 + f0 + tc4);
    const float4 bin_ = *(const float4*)(b_ih + 512 + f0 + tc4);
    const float4 bhrB = *(const float4*)(b_hh + f0 + tc4);
    const float4 bhzB = *(const float4*)(b_hh + 256 + f0 + tc4);
    const float4 bhnB = *(const float4*)(b_hh + 512 + f0 + tc4);

    #pragma unroll
    for (int i = 0; i < 4; ++i) {
        int row = br + tr + i;
        if (row >= N_NODES) continue;
        float4 hv = *(const float4*)(h + (size_t)row * 256 + f0 + tc4);
        float4 o;
        {
            float r = sigm(axr[i][0] + bir.x + ahr[i][0] + bhrB.x);
            float z = sigm(axz[i][0] + biz.x + ahz[i][0] + bhzB.x);
            float n = tanhf(axn[i][0] + bin_.x + r * (ahn[i][0] + bhnB.x));
            o.x = (1.f - z) * n + z * hv.x;
        }
        {
            float r = sigm(axr[i][1] + bir.y + ahr[i][1] + bhrB.y);
            float z = sigm(axz[i][1] + biz.y + ahz[i][1] + bhzB.y);
            float n = tanhf(axn[i][1] + bin_.y + r * (ahn[i][1] + bhnB.y));
            o.y = (1.f - z) * n + z * hv.y;
        }
        {
            float r = sigm(axr[i][2] + bir.z + ahr[i][2] + bhrB.z);
            float z = sigm(axz[i][2] + biz.z + ahz[i][2] + bhzB.z);
            float n = tanhf(axn[i][2] + bin_.z + r * (ahn[i][2] + bhnB.z));
            o.z = (1.f - z) * n + z * hv.z;
        }
        {
            float r = sigm(axr[i][3] + bir.w + ahr[i][3] + bhrB.w);
            float z = sigm(axz[i][3] + biz.w + ahz[i][3] + bhzB.w);
            float n = tanhf(axn[i][3] + bin_.w + r * (ahn[i][3] + bhnB.w));
            o.w = (1.f - z) * n + z * hv.w;
        }
        *(float4*)(hN + (size_t)row * 256 + f0 + tc4) = o;
    }
}

// ---------------- readout ----------------
__global__ __launch_bounds__(256) void k_readout1(const float* __restrict__ h,
                                                  const int* __restrict__ gid,
                                                  float* __restrict__ hg) {
    int row0 = blockIdx.x * 32;
    if (row0 >= N_NODES) return;
    int f = threadIdx.x;
    int end = row0 + 32; if (end > N_NODES) end = N_NODES;
    float acc = 0.f;
    int cur = gid[row0];
    for (int r = row0; r < end; ++r) {
        int g = gid[r];
        if (g != cur) {
            atomicAdd(&hg[cur * HIDDEN + f], acc);
            acc = 0.f; cur = g;
        }
        float x = h[(size_t)r * HIDDEN + f];
        acc += (x > 0.f) ? x : 0.f;
    }
    atomicAdd(&hg[cur * HIDDEN + f], acc);
}

__global__ __launch_bounds__(256) void k_readout2(const float* __restrict__ hg,
                                                  const float* __restrict__ Wc,
                                                  const float* __restrict__ bc,
                                                  float* __restrict__ out) {
    __shared__ float s[256];
    int g = blockIdx.x;
    int f = threadIdx.x;
    s[f] = hg[g * HIDDEN + f] * Wc[f];
    __syncthreads();
    for (int off = 128; off > 0; off >>= 1) {
        if (f < off) s[f] += s[f + off];
        __syncthreads();
    }
    if (f == 0) out[g] = 1.0f / (1.0f + expf(-(s[0] + bc[0])));
}

// ---------------- launch ----------------
extern "C" void kernel_launch(void* const* d_in, const int* in_sizes, int n_in,
                              void* d_out, int out_size, void* d_ws, size_t ws_size,
                              hipStream_t stream) {
    const float* feat  = (const float*)d_in[0];
    const float* W     = (const float*)d_in[1];
    const float* W_ih  = (const float*)d_in[2];
    const float* W_hh  = (const float*)d_in[3];
    const float* b_ih  = (const float*)d_in[4];
    const float* b_hh  = (const float*)d_in[5];
    const float* Wc    = (const float*)d_in[6];
    const float* bc    = (const float*)d_in[7];
    const int*   src   = (const int*)d_in[8];
    const int*   dst   = (const int*)d_in[9];
    const int*   etype = (const int*)d_in[10];
    const int*   gid   = (const int*)d_in[11];
    float* out = (float*)d_out;

    char* ws = (char*)d_ws;
    size_t off = 0;
    auto alloc = [&](size_t bytes) {
        void* p = ws + off;
        off += (bytes + 255) & ~(size_t)255;
        return p;
    };
    // total ~162.3 MB
    float* hA   = (float*)alloc((size_t)N_NODES * HIDDEN * 4);   // 51.2 MB
    float* hB   = (float*)alloc((size_t)N_NODES * HIDDEN * 4);   // 51.2 MB
    float* a    = (float*)alloc((size_t)N_NODES * HIDDEN * 4);   // 51.2 MB
    int* bufA   = (int*)alloc((size_t)(NKEYS + 1) * 4);          // counts, then ptr
    int* bufB   = (int*)alloc((size_t)NKEYS * 4);                // lexcl, then cursor
    int* ebuf   = (int*)alloc((size_t)N_EDGES * 4);              // src id per bucketed edge
    int* bsums  = (int*)alloc((size_t)2048 * 4);
    float* hg   = (float*)alloc((size_t)NUM_GRAPHS * HIDDEN * 4);
    (void)ws_size; (void)n_in; (void)in_sizes; (void)out_size;

    const int SCAN_BLOCKS = (NKEYS + SCAN_T - 1) / SCAN_T;       // 1270

    // ---- CSR build, bucketed by (etype, dst) ----
    hipMemsetAsync(bufA, 0, (size_t)NKEYS * 4, stream);
    k_hist<<<(N_EDGES + 255) / 256, 256, 0, stream>>>(dst, etype, bufA);
    k_scan1<<<SCAN_BLOCKS, SCAN_T, 0, stream>>>(bufA, bufB, bsums, NKEYS);
    k_scan2<<<1, 256, 0, stream>>>(bsums, SCAN_BLOCKS, bufA);
    k_scan3<<<SCAN_BLOCKS, SCAN_T, 0, stream>>>(bufB, bsums, bufA, NKEYS);
    hipMemcpyAsync(bufB, bufA, (size_t)NKEYS * 4, hipMemcpyDeviceToDevice, stream);
    k_place<<<(N_EDGES + 255) / 256, 256, 0, stream>>>(dst, etype, src, bufB, ebuf);

    // ---- h0 ----
    k_init_h<<<(N_NODES * 64 + 255) / 256, 256, 0, stream>>>(feat, hA);

    float* hc = hA;
    float* hn = hB;
    const dim3 gMsg((N_NODES + 63) / 64, 1);                     // 782
    const dim3 gGru((N_NODES + 63) / 64, HIDDEN / 64);           // 782 x 4

    for (int step = 0; step < N_STEPS; ++step) {
        k_msg<<<gMsg, 256, 0, stream>>>(ebuf, bufA, hc, W, a);
        k_gru<<<gGru, 256, 0, stream>>>(a, hc, W_ih, W_hh, b_ih, b_hh, hn);
        float* tmp = hc; hc = hn; hn = tmp;
    }

    // ---- readout ----
    hipMemsetAsync(hg, 0, (size_t)NUM_GRAPHS * HIDDEN * 4, stream);
    k_readout1<<<(N_NODES + 31) / 32, 256, 0, stream>>>(hc, gid, hg);
    k_readout2<<<NUM_GRAPHS, 256, 0, stream>>>(hg, Wc, bc, out);
}

// Round 7
// 14658.661 us; speedup vs baseline: 1.2349x; 1.2349x over previous
//
#include <hip/hip_runtime.h>
#include <math.h>

#define N_NODES   50000
#define N_EDGES   800000
#define IN_DIM    128
#define HIDDEN    256
#define N_ETYPES  13
#define N_STEPS   6
#define NUM_GRAPHS 64
#define NKEYS     (N_ETYPES * N_NODES)
#define SCAN_T    512

typedef __attribute__((ext_vector_type(8))) short bf16x8;
typedef __attribute__((ext_vector_type(4))) float f32x4;

// ---------------- init h0 = [feat | zeros] ----------------
__global__ __launch_bounds__(256) void k_init_h(const float* __restrict__ feat,
                                                float* __restrict__ h) {
    int i = blockIdx.x * 256 + threadIdx.x;          // float4 index over N*64
    if (i >= N_NODES * 64) return;
    int v = i >> 6;
    int q = i & 63;
    float4 val;
    if (q < 32) val = ((const float4*)(feat + (size_t)v * IN_DIM))[q];
    else        val = make_float4(0.f, 0.f, 0.f, 0.f);
    ((float4*)(h + (size_t)v * HIDDEN))[q] = val;
}

// ---------------- split W (message) into bf16 hi/lo, transposed to [t][n][k]
__global__ __launch_bounds__(256) void k_splitW(const float* __restrict__ W,
                                                short* __restrict__ Whi,
                                                short* __restrict__ Wlo) {
    int i = blockIdx.x * 256 + threadIdx.x;          // over 13*256*256
    if (i >= N_ETYPES * 65536) return;
    int t = i >> 16, rem = i & 65535, n = rem >> 8, k = rem & 255;
    float x = W[(size_t)t * 65536 + k * 256 + n];    // W is [t][k][n]
    unsigned u = __float_as_uint(x);
    unsigned short hb = (unsigned short)(u >> 16);   // truncate
    float hf = __uint_as_float((unsigned)hb << 16);
    float l = x - hf;
    unsigned short lb = (unsigned short)(__float_as_uint(l) >> 16);
    Whi[i] = (short)hb;                              // i == t*65536 + n*256 + k
    Wlo[i] = (short)lb;
}

// ---------------- split a linear weight [768][256] elementwise (no transpose:
// nn.Linear rows are already the MFMA B-fragment [n][k] layout) --------------
__global__ __launch_bounds__(256) void k_splitLin(const float* __restrict__ Wsrc,
                                                  short* __restrict__ hi,
                                                  short* __restrict__ lo, int n) {
    int i = blockIdx.x * 256 + threadIdx.x;
    if (i >= n) return;
    float x = Wsrc[i];
    unsigned u = __float_as_uint(x);
    unsigned short hb = (unsigned short)(u >> 16);
    float hf = __uint_as_float((unsigned)hb << 16);
    float l = x - hf;
    unsigned short lb = (unsigned short)(__float_as_uint(l) >> 16);
    hi[i] = (short)hb;
    lo[i] = (short)lb;
}

// ---------------- CSR build: histogram / scan / place ----------------
__global__ __launch_bounds__(256) void k_hist(const int* __restrict__ dst,
                                              const int* __restrict__ et,
                                              int* __restrict__ counts) {
    int e = blockIdx.x * 256 + threadIdx.x;
    if (e >= N_EDGES) return;
    int key = et[e] * N_NODES + dst[e];
    atomicAdd(&counts[key], 1);
}

__global__ __launch_bounds__(SCAN_T) void k_scan1(const int* __restrict__ in,
                                                  int* __restrict__ lexcl,
                                                  int* __restrict__ bsums, int n) {
    __shared__ int s[SCAN_T];
    int i = blockIdx.x * SCAN_T + threadIdx.x;
    int v = (i < n) ? in[i] : 0;
    s[threadIdx.x] = v;
    __syncthreads();
    for (int off = 1; off < SCAN_T; off <<= 1) {
        int t = (threadIdx.x >= off) ? s[threadIdx.x - off] : 0;
        __syncthreads();
        s[threadIdx.x] += t;
        __syncthreads();
    }
    if (i < n) lexcl[i] = s[threadIdx.x] - v;
    if (threadIdx.x == SCAN_T - 1) bsums[blockIdx.x] = s[SCAN_T - 1];
}

__global__ __launch_bounds__(256) void k_scan2(int* __restrict__ bsums, int nb,
                                               int* __restrict__ ptr) {
    __shared__ int s[256];
    int tid = threadIdx.x;
    const int C = (nb + 255) / 256;                  // <= 8
    int vals[8];
    int base = tid * C;
    int sum = 0;
    for (int i = 0; i < C; ++i) {
        int idx = base + i;
        int v = (idx < nb) ? bsums[idx] : 0;
        vals[i] = sum;
        sum += v;
    }
    s[tid] = sum;
    __syncthreads();
    int own = sum;
    for (int off = 1; off < 256; off <<= 1) {
        int t = (tid >= off) ? s[tid - off] : 0;
        __syncthreads();
        s[tid] += t;
        __syncthreads();
    }
    int exclBlk = s[tid] - own;
    for (int i = 0; i < C; ++i) {
        int idx = base + i;
        if (idx < nb) bsums[idx] = exclBlk + vals[i];
    }
    if (tid == 0) ptr[NKEYS] = N_EDGES;              // end sentinel
}

__global__ __launch_bounds__(SCAN_T) void k_scan3(const int* __restrict__ lexcl,
                                                  const int* __restrict__ bsums,
                                                  int* __restrict__ ptr, int n) {
    int i = blockIdx.x * SCAN_T + threadIdx.x;
    if (i < n) ptr[i] = lexcl[i] + bsums[blockIdx.x];
}

// ebuf[pos] packs (dst<<16)|src (both < 65536); unsigned arithmetic (dst<<16
// would overflow signed int).
__global__ __launch_bounds__(256) void k_place(const int* __restrict__ dst,
                                               const int* __restrict__ et,
                                               const int* __restrict__ src,
                                               int* __restrict__ cursor,
                                               unsigned* __restrict__ ebuf) {
    int e = blockIdx.x * 256 + threadIdx.x;
    if (e >= N_EDGES) return;
    int d = dst[e];
    int key = et[e] * N_NODES + d;
    int pos = atomicAdd(&cursor[key], 1);
    ebuf[pos] = ((unsigned)d << 16) | (unsigned)src[e];
}

// ---------------- fused message kernel: edge-parallel gather + MFMA --------
__device__ __forceinline__ void split8(const float4& A, const float4& B,
                                       bf16x8& hi, bf16x8& lo) {
    float x[8] = {A.x, A.y, A.z, A.w, B.x, B.y, B.z, B.w};
    #pragma unroll
    for (int e = 0; e < 8; ++e) {
        unsigned u = __float_as_uint(x[e]);
        unsigned short hb = (unsigned short)(u >> 16);
        float hf = __uint_as_float((unsigned)hb << 16);
        float l = x[e] - hf;
        unsigned short lb = (unsigned short)(__float_as_uint(l) >> 16);
        hi[e] = (short)hb;
        lo[e] = (short)lb;
    }
}

__global__ __launch_bounds__(256, 2) void k_msg(const unsigned* __restrict__ ebuf,
                                                const int* __restrict__ ptr,
                                                const float* __restrict__ h,
                                                const short* __restrict__ Whi,
                                                const short* __restrict__ Wlo,
                                                float* __restrict__ a) {
    __shared__ float4 Sh4[64 * 64];                  // 64 rows x 256 f32, 64 KB
    const int br   = blockIdx.x * 64;
    const int tid  = threadIdx.x;
    const int l    = tid & 63;
    const int w    = tid >> 6;                       // wave: cols [64w, 64w+64)
    const int ln15 = l & 15;
    const int lhi  = l >> 4;                         // 0..3
    const int g    = tid >> 4;                       // gather group 0..15
    const int q    = tid & 15;                       // lane in group
    const float4* h4 = (const float4*)h;
    float* shf = (float*)Sh4;

    f32x4 acc[4][4] = {};                            // [row-frag][col-frag]

    for (int t = 0; t < N_ETYPES; ++t) {
        // ---- zero Sh
        float4 z4 = make_float4(0.f, 0.f, 0.f, 0.f);
        #pragma unroll
        for (int i = 0; i < 16; ++i) Sh4[tid + i * 256] = z4;
        __syncthreads();
        // ---- edge-parallel gather with LDS atomics
        {
            int base = t * N_NODES + br;
            int beg  = ptr[base];
            int endk = (br + 64 <= N_NODES) ? (base + 64) : (t * N_NODES + N_NODES);
            int end  = ptr[endk];
            for (int i = beg + g; i < end; i += 16) {
                unsigned pk = ebuf[i];
                int s = (int)(pk & 0xFFFFu);
                int r = (int)(pk >> 16) - br;        // 0..63 by construction
                int sw = r & 7;
                #pragma unroll
                for (int j = 0; j < 4; ++j) {
                    float4 v = h4[(size_t)s * 64 + j * 16 + q];
                    int jj = (j * 16 + q) ^ sw;      // swizzled float4 col
                    float* p = shf + ((r * 64 + jj) << 2);
                    atomicAdd(p + 0, v.x);
                    atomicAdd(p + 1, v.y);
                    atomicAdd(p + 2, v.z);
                    atomicAdd(p + 3, v.w);
                }
            }
        }
        __syncthreads();
        // ---- split-bf16 MFMA GEMM: acc += Sh @ W[t][:, 64w..64w+64)
        const short* WH = Whi + ((size_t)t << 16);
        const short* WL = Wlo + ((size_t)t << 16);
        #pragma unroll 2
        for (int K0 = 0; K0 < 8; ++K0) {             // K = K0*32
            bf16x8 bh[4], bl[4];
            #pragma unroll
            for (int cb = 0; cb < 4; ++cb) {
                int col = (w << 6) + (cb << 4) + ln15;
                size_t off = (size_t)col * 256 + (K0 << 5) + (lhi << 3);
                bh[cb] = *reinterpret_cast<const bf16x8*>(WH + off);
                bl[cb] = *reinterpret_cast<const bf16x8*>(WL + off);
            }
            #pragma unroll
            for (int rf = 0; rf < 4; ++rf) {
                int row = (rf << 4) + ln15;
                int j0  = (K0 << 3) + (lhi << 1);
                int sw  = row & 7;
                float4 a0 = Sh4[row * 64 + (j0 ^ sw)];
                float4 a1 = Sh4[row * 64 + ((j0 + 1) ^ sw)];
                bf16x8 ah, al;
                split8(a0, a1, ah, al);
                #pragma unroll
                for (int cb = 0; cb < 4; ++cb) {
                    acc[rf][cb] = __builtin_amdgcn_mfma_f32_16x16x32_bf16(ah, bh[cb], acc[rf][cb], 0, 0, 0);
                    acc[rf][cb] = __builtin_amdgcn_mfma_f32_16x16x32_bf16(ah, bl[cb], acc[rf][cb], 0, 0, 0);
                    acc[rf][cb] = __builtin_amdgcn_mfma_f32_16x16x32_bf16(al, bh[cb], acc[rf][cb], 0, 0, 0);
                }
            }
        }
        __syncthreads();                             // Sh reused next etype
    }
    // ---- C write: C/D layout col=lane&15, row=(lane>>4)*4+reg
    #pragma unroll
    for (int rf = 0; rf < 4; ++rf) {
        #pragma unroll
        for (int m = 0; m < 4; ++m) {
            int row = br + (rf << 4) + (lhi << 2) + m;
            if (row < N_NODES) {
                #pragma unroll
                for (int cb = 0; cb < 4; ++cb) {
                    int col = (w << 6) + (cb << 4) + ln15;
                    a[(size_t)row * 256 + col] = acc[rf][cb][m];
                }
            }
        }
    }
}

// ---------------- MFMA GRU kernel ----------------
// Block = 64 rows x 64 f-cols; wave w owns rows [16w,16w+16).
// Per wave: 6 gate-tiles (xr,xz,xn,hr,hz,hn) of 16x64, K=256, split-bf16
// MFMA (3 products). A-frags loaded per-lane from global (L2/L3-resident),
// B-frags from pre-split W_ih/W_hh (nn.Linear rows are already [n][k]).
__device__ __forceinline__ float sigm(float x) { return 1.0f / (1.0f + expf(-x)); }

__global__ __launch_bounds__(256, 2) void k_gru(const float* __restrict__ a,
                                                const float* __restrict__ h,
                                                const short* __restrict__ WihH,
                                                const short* __restrict__ WihL,
                                                const short* __restrict__ WhhH,
                                                const short* __restrict__ WhhL,
                                                const float* __restrict__ b_ih,
                                                const float* __restrict__ b_hh,
                                                float* __restrict__ hN) {
    const int br   = blockIdx.x * 64;
    const int f0   = blockIdx.y * 64;
    const int tid  = threadIdx.x;
    const int w    = tid >> 6;
    const int l    = tid & 63;
    const int ln15 = l & 15;
    const int lhi  = l >> 4;

    f32x4 accx[3][4] = {};                           // [gate][col-frag]
    f32x4 acch[3][4] = {};

    int rowA = br + (w << 4) + ln15;                 // A-frag row for this lane
    if (rowA >= N_NODES) rowA = N_NODES - 1;         // clamp, stores guarded
    const float* aRow = a + (size_t)rowA * 256;
    const float* hRow = h + (size_t)rowA * 256;

    #pragma unroll 2
    for (int K0 = 0; K0 < 8; ++K0) {
        const int koff = (K0 << 5) + (lhi << 3);
        float4 av0 = *(const float4*)(aRow + koff);
        float4 av1 = *(const float4*)(aRow + koff + 4);
        float4 hv0 = *(const float4*)(hRow + koff);
        float4 hv1 = *(const float4*)(hRow + koff + 4);
        bf16x8 aH, aL, hH, hL;
        split8(av0, av1, aH, aL);
        split8(hv0, hv1, hH, hL);
        #pragma unroll
        for (int g = 0; g < 3; ++g) {
            #pragma unroll
            for (int cb = 0; cb < 4; ++cb) {
                int col = g * 256 + f0 + (cb << 4) + ln15;
                size_t off = (size_t)col * 256 + koff;
                bf16x8 bH = *reinterpret_cast<const bf16x8*>(WihH + off);
                bf16x8 bL = *reinterpret_cast<const bf16x8*>(WihL + off);
                accx[g][cb] = __builtin_amdgcn_mfma_f32_16x16x32_bf16(aH, bH, accx[g][cb], 0, 0, 0);
                accx[g][cb] = __builtin_amdgcn_mfma_f32_16x16x32_bf16(aH, bL, accx[g][cb], 0, 0, 0);
                accx[g][cb] = __builtin_amdgcn_mfma_f32_16x16x32_bf16(aL, bH, accx[g][cb], 0, 0, 0);
                bH = *reinterpret_cast<const bf16x8*>(WhhH + off);
                bL = *reinterpret_cast<const bf16x8*>(WhhL + off);
                acch[g][cb] = __builtin_amdgcn_mfma_f32_16x16x32_bf16(hH, bH, acch[g][cb], 0, 0, 0);
                acch[g][cb] = __builtin_amdgcn_mfma_f32_16x16x32_bf16(hH, bL, acch[g][cb], 0, 0, 0);
                acch[g][cb] = __builtin_amdgcn_mfma_f32_16x16x32_bf16(hL, bH, acch[g][cb], 0, 0, 0);
            }
        }
    }
    // ---- gate epilogue; C/D frag: col = 16cb+ln15, row = 16w + 4*lhi + m
    #pragma unroll
    for (int cb = 0; cb < 4; ++cb) {
        int f = f0 + (cb << 4) + ln15;
        float bxr = b_ih[f], bxz = b_ih[256 + f], bxn = b_ih[512 + f];
        float bhr = b_hh[f], bhz = b_hh[256 + f], bhn = b_hh[512 + f];
        #pragma unroll
        for (int m = 0; m < 4; ++m) {
            int row = br + (w << 4) + (lhi << 2) + m;
            if (row >= N_NODES) continue;
            float hv = h[(size_t)row * 256 + f];
            float r = sigm(accx[0][cb][m] + bxr + acch[0][cb][m] + bhr);
            float z = sigm(accx[1][cb][m] + bxz + acch[1][cb][m] + bhz);
            float n = tanhf(accx[2][cb][m] + bxn + r * (acch[2][cb][m] + bhn));
            hN[(size_t)row * 256 + f] = (1.f - z) * n + z * hv;
        }
    }
}

// ---------------- readout ----------------
__global__ __launch_bounds__(256) void k_readout1(const float* __restrict__ h,
                                                  const int* __restrict__ gid,
                                                  float* __restrict__ hg) {
    int row0 = blockIdx.x * 32;
    if (row0 >= N_NODES) return;
    int f = threadIdx.x;
    int end = row0 + 32; if (end > N_NODES) end = N_NODES;
    float acc = 0.f;
    int cur = gid[row0];
    for (int r = row0; r < end; ++r) {
        int g = gid[r];
        if (g != cur) {
            atomicAdd(&hg[cur * HIDDEN + f], acc);
            acc = 0.f; cur = g;
        }
        float x = h[(size_t)r * HIDDEN + f];
        acc += (x > 0.f) ? x : 0.f;
    }
    atomicAdd(&hg[cur * HIDDEN + f], acc);
}

__global__ __launch_bounds__(256) void k_readout2(const float* __restrict__ hg,
                                                  const float* __restrict__ Wc,
                                                  const float* __restrict__ bc,
                                                  float* __restrict__ out) {
    __shared__ float s[256];
    int g = blockIdx.x;
    int f = threadIdx.x;
    s[f] = hg[g * HIDDEN + f] * Wc[f];
    __syncthreads();
    for (int off = 128; off > 0; off >>= 1) {
        if (f < off) s[f] += s[f + off];
        __syncthreads();
    }
    if (f == 0) out[g] = 1.0f / (1.0f + expf(-(s[0] + bc[0])));
}

// ---------------- launch ----------------
extern "C" void kernel_launch(void* const* d_in, const int* in_sizes, int n_in,
                              void* d_out, int out_size, void* d_ws, size_t ws_size,
                              hipStream_t stream) {
    const float* feat  = (const float*)d_in[0];
    const float* W     = (const float*)d_in[1];
    const float* W_ih  = (const float*)d_in[2];
    const float* W_hh  = (const float*)d_in[3];
    const float* b_ih  = (const float*)d_in[4];
    const float* b_hh  = (const float*)d_in[5];
    const float* Wc    = (const float*)d_in[6];
    const float* bc    = (const float*)d_in[7];
    const int*   src   = (const int*)d_in[8];
    const int*   dst   = (const int*)d_in[9];
    const int*   etype = (const int*)d_in[10];
    const int*   gid   = (const int*)d_in[11];
    float* out = (float*)d_out;

    char* ws = (char*)d_ws;
    size_t off = 0;
    auto alloc = [&](size_t bytes) {
        void* p = ws + off;
        off += (bytes + 255) & ~(size_t)255;
        return p;
    };
    // total ~168 MB
    float* hA   = (float*)alloc((size_t)N_NODES * HIDDEN * 4);   // 51.2 MB
    float* hB   = (float*)alloc((size_t)N_NODES * HIDDEN * 4);   // 51.2 MB
    float* a    = (float*)alloc((size_t)N_NODES * HIDDEN * 4);   // 51.2 MB
    int* bufA   = (int*)alloc((size_t)(NKEYS + 1) * 4);          // counts, then ptr
    int* bufB   = (int*)alloc((size_t)NKEYS * 4);                // lexcl, then cursor
    unsigned* ebuf = (unsigned*)alloc((size_t)N_EDGES * 4);      // (dst<<16)|src
    int* bsums  = (int*)alloc((size_t)2048 * 4);
    float* hg   = (float*)alloc((size_t)NUM_GRAPHS * HIDDEN * 4);
    short* Whi  = (short*)alloc((size_t)N_ETYPES * 65536 * 2);   // 1.7 MB
    short* Wlo  = (short*)alloc((size_t)N_ETYPES * 65536 * 2);   // 1.7 MB
    short* WihH = (short*)alloc((size_t)768 * 256 * 2);          // 393 KB
    short* WihL = (short*)alloc((size_t)768 * 256 * 2);
    short* WhhH = (short*)alloc((size_t)768 * 256 * 2);
    short* WhhL = (short*)alloc((size_t)768 * 256 * 2);
    (void)ws_size; (void)n_in; (void)in_sizes; (void)out_size;

    const int SCAN_BLOCKS = (NKEYS + SCAN_T - 1) / SCAN_T;       // 1270
    const int NLIN = 768 * 256;

    // ---- CSR build, bucketed by (etype, dst) ----
    hipMemsetAsync(bufA, 0, (size_t)NKEYS * 4, stream);
    k_hist<<<(N_EDGES + 255) / 256, 256, 0, stream>>>(dst, etype, bufA);
    k_scan1<<<SCAN_BLOCKS, SCAN_T, 0, stream>>>(bufA, bufB, bsums, NKEYS);
    k_scan2<<<1, 256, 0, stream>>>(bsums, SCAN_BLOCKS, bufA);
    k_scan3<<<SCAN_BLOCKS, SCAN_T, 0, stream>>>(bufB, bsums, bufA, NKEYS);
    hipMemcpyAsync(bufB, bufA, (size_t)NKEYS * 4, hipMemcpyDeviceToDevice, stream);
    k_place<<<(N_EDGES + 255) / 256, 256, 0, stream>>>(dst, etype, src, bufB, ebuf);

    // ---- weight splits (once) + h0 ----
    k_splitW<<<(N_ETYPES * 65536 + 255) / 256, 256, 0, stream>>>(W, Whi, Wlo);
    k_splitLin<<<(NLIN + 255) / 256, 256, 0, stream>>>(W_ih, WihH, WihL, NLIN);
    k_splitLin<<<(NLIN + 255) / 256, 256, 0, stream>>>(W_hh, WhhH, WhhL, NLIN);
    k_init_h<<<(N_NODES * 64 + 255) / 256, 256, 0, stream>>>(feat, hA);

    float* hc = hA;
    float* hn = hB;
    const dim3 gMsg((N_NODES + 63) / 64, 1);                     // 782
    const dim3 gGru((N_NODES + 63) / 64, HIDDEN / 64);           // 782 x 4

    for (int step = 0; step < N_STEPS; ++step) {
        k_msg<<<gMsg, 256, 0, stream>>>(ebuf, bufA, hc, Whi, Wlo, a);
        k_gru<<<gGru, 256, 0, stream>>>(a, hc, WihH, WihL, WhhH, WhhL,
                                        b_ih, b_hh, hn);
        float* tmp = hc; hc = hn; hn = tmp;
    }

    // ---- readout ----
    hipMemsetAsync(hg, 0, (size_t)NUM_GRAPHS * HIDDEN * 4, stream);
    k_readout1<<<(N_NODES + 31) / 32, 256, 0, stream>>>(hc, gid, hg);
    k_readout2<<<NUM_GRAPHS, 256, 0, stream>>>(hg, Wc, bc, out);
}

// Round 8
// 13934.460 us; speedup vs baseline: 1.2991x; 1.0520x over previous
//
#include <hip/hip_runtime.h>
#include <math.h>

#define N_NODES   50000
#define N_EDGES   800000
#define IN_DIM    128
#define HIDDEN    256
#define N_ETYPES  13
#define N_STEPS   6
#define NUM_GRAPHS 64
#define NKEYS     (N_ETYPES * N_NODES)
#define SCAN_T    512

typedef __attribute__((ext_vector_type(8))) short bf16x8;
typedef __attribute__((ext_vector_type(4))) float f32x4;

// ---------------- init h0 = [feat | zeros] ----------------
__global__ __launch_bounds__(256) void k_init_h(const float* __restrict__ feat,
                                                float* __restrict__ h) {
    int i = blockIdx.x * 256 + threadIdx.x;          // float4 index over N*64
    if (i >= N_NODES * 64) return;
    int v = i >> 6;
    int q = i & 63;
    float4 val;
    if (q < 32) val = ((const float4*)(feat + (size_t)v * IN_DIM))[q];
    else        val = make_float4(0.f, 0.f, 0.f, 0.f);
    ((float4*)(h + (size_t)v * HIDDEN))[q] = val;
}

// ---------------- split W (message) into bf16 hi/lo, transposed to [t][n][k]
__global__ __launch_bounds__(256) void k_splitW(const float* __restrict__ W,
                                                short* __restrict__ Whi,
                                                short* __restrict__ Wlo) {
    int i = blockIdx.x * 256 + threadIdx.x;          // over 13*256*256
    if (i >= N_ETYPES * 65536) return;
    int t = i >> 16, rem = i & 65535, n = rem >> 8, k = rem & 255;
    float x = W[(size_t)t * 65536 + k * 256 + n];    // W is [t][k][n]
    unsigned u = __float_as_uint(x);
    unsigned short hb = (unsigned short)(u >> 16);   // truncate
    float hf = __uint_as_float((unsigned)hb << 16);
    float l = x - hf;
    unsigned short lb = (unsigned short)(__float_as_uint(l) >> 16);
    Whi[i] = (short)hb;                              // i == t*65536 + n*256 + k
    Wlo[i] = (short)lb;
}

// ---------------- split a linear weight [768][256] elementwise (no transpose:
// nn.Linear rows are already the MFMA B-fragment [n][k] layout) --------------
__global__ __launch_bounds__(256) void k_splitLin(const float* __restrict__ Wsrc,
                                                  short* __restrict__ hi,
                                                  short* __restrict__ lo, int n) {
    int i = blockIdx.x * 256 + threadIdx.x;
    if (i >= n) return;
    float x = Wsrc[i];
    unsigned u = __float_as_uint(x);
    unsigned short hb = (unsigned short)(u >> 16);
    float hf = __uint_as_float((unsigned)hb << 16);
    float l = x - hf;
    unsigned short lb = (unsigned short)(__float_as_uint(l) >> 16);
    hi[i] = (short)hb;
    lo[i] = (short)lb;
}

// ---------------- CSR build: histogram / scan / place ----------------
__global__ __launch_bounds__(256) void k_hist(const int* __restrict__ dst,
                                              const int* __restrict__ et,
                                              int* __restrict__ counts) {
    int e = blockIdx.x * 256 + threadIdx.x;
    if (e >= N_EDGES) return;
    int key = et[e] * N_NODES + dst[e];
    atomicAdd(&counts[key], 1);
}

__global__ __launch_bounds__(SCAN_T) void k_scan1(const int* __restrict__ in,
                                                  int* __restrict__ lexcl,
                                                  int* __restrict__ bsums, int n) {
    __shared__ int s[SCAN_T];
    int i = blockIdx.x * SCAN_T + threadIdx.x;
    int v = (i < n) ? in[i] : 0;
    s[threadIdx.x] = v;
    __syncthreads();
    for (int off = 1; off < SCAN_T; off <<= 1) {
        int t = (threadIdx.x >= off) ? s[threadIdx.x - off] : 0;
        __syncthreads();
        s[threadIdx.x] += t;
        __syncthreads();
    }
    if (i < n) lexcl[i] = s[threadIdx.x] - v;
    if (threadIdx.x == SCAN_T - 1) bsums[blockIdx.x] = s[SCAN_T - 1];
}

__global__ __launch_bounds__(256) void k_scan2(int* __restrict__ bsums, int nb,
                                               int* __restrict__ ptr) {
    __shared__ int s[256];
    int tid = threadIdx.x;
    const int C = (nb + 255) / 256;                  // <= 8
    int vals[8];
    int base = tid * C;
    int sum = 0;
    for (int i = 0; i < C; ++i) {
        int idx = base + i;
        int v = (idx < nb) ? bsums[idx] : 0;
        vals[i] = sum;
        sum += v;
    }
    s[tid] = sum;
    __syncthreads();
    int own = sum;
    for (int off = 1; off < 256; off <<= 1) {
        int t = (tid >= off) ? s[tid - off] : 0;
        __syncthreads();
        s[tid] += t;
        __syncthreads();
    }
    int exclBlk = s[tid] - own;
    for (int i = 0; i < C; ++i) {
        int idx = base + i;
        if (idx < nb) bsums[idx] = exclBlk + vals[i];
    }
    if (tid == 0) ptr[NKEYS] = N_EDGES;              // end sentinel
}

__global__ __launch_bounds__(SCAN_T) void k_scan3(const int* __restrict__ lexcl,
                                                  const int* __restrict__ bsums,
                                                  int* __restrict__ ptr, int n) {
    int i = blockIdx.x * SCAN_T + threadIdx.x;
    if (i < n) ptr[i] = lexcl[i] + bsums[blockIdx.x];
}

// ebuf[pos] packs (dst<<16)|src (both < 65536); unsigned arithmetic (dst<<16
// would overflow signed int).
__global__ __launch_bounds__(256) void k_place(const int* __restrict__ dst,
                                               const int* __restrict__ et,
                                               const int* __restrict__ src,
                                               int* __restrict__ cursor,
                                               unsigned* __restrict__ ebuf) {
    int e = blockIdx.x * 256 + threadIdx.x;
    if (e >= N_EDGES) return;
    int d = dst[e];
    int key = et[e] * N_NODES + d;
    int pos = atomicAdd(&cursor[key], 1);
    ebuf[pos] = ((unsigned)d << 16) | (unsigned)src[e];
}

// ---------------- fused message kernel: edge-parallel gather + MFMA --------
// 32-row tile (Sh = 32 KB) -> 4 blocks/CU resident vs 2 at 64 rows: the R7
// profile showed all pipes <6% busy at 15% occupancy — latency-bound on the
// 13-etype barrier chain. More resident blocks = more cross-block overlap.
__device__ __forceinline__ void split8(const float4& A, const float4& B,
                                       bf16x8& hi, bf16x8& lo) {
    float x[8] = {A.x, A.y, A.z, A.w, B.x, B.y, B.z, B.w};
    #pragma unroll
    for (int e = 0; e < 8; ++e) {
        unsigned u = __float_as_uint(x[e]);
        unsigned short hb = (unsigned short)(u >> 16);
        float hf = __uint_as_float((unsigned)hb << 16);
        float l = x[e] - hf;
        unsigned short lb = (unsigned short)(__float_as_uint(l) >> 16);
        hi[e] = (short)hb;
        lo[e] = (short)lb;
    }
}

__global__ __launch_bounds__(256, 4) void k_msg(const unsigned* __restrict__ ebuf,
                                                const int* __restrict__ ptr,
                                                const float* __restrict__ h,
                                                const short* __restrict__ Whi,
                                                const short* __restrict__ Wlo,
                                                float* __restrict__ a) {
    __shared__ float4 Sh4[32 * 64];                  // 32 rows x 256 f32, 32 KB
    const int br   = blockIdx.x * 32;
    const int tid  = threadIdx.x;
    const int l    = tid & 63;
    const int w    = tid >> 6;                       // wave: cols [64w, 64w+64)
    const int ln15 = l & 15;
    const int lhi  = l >> 4;                         // 0..3
    const int g    = tid >> 4;                       // gather group 0..15
    const int q    = tid & 15;                       // lane in group
    const float4* h4 = (const float4*)h;
    float* shf = (float*)Sh4;

    f32x4 acc[2][4] = {};                            // [row-frag][col-frag]

    for (int t = 0; t < N_ETYPES; ++t) {
        // ---- zero Sh (2048 float4 / 256 threads = 8 each)
        float4 z4 = make_float4(0.f, 0.f, 0.f, 0.f);
        #pragma unroll
        for (int i = 0; i < 8; ++i) Sh4[tid + i * 256] = z4;
        __syncthreads();
        // ---- edge-parallel gather with LDS atomics
        {
            int base = t * N_NODES + br;
            int endk = (br + 32 <= N_NODES) ? (base + 32) : (t * N_NODES + N_NODES);
            int beg  = ptr[base];
            int end  = ptr[endk];
            for (int i = beg + g; i < end; i += 16) {
                unsigned pk = ebuf[i];
                int s = (int)(pk & 0xFFFFu);
                int r = (int)(pk >> 16) - br;        // 0..31 by construction
                int sw = r & 7;
                #pragma unroll
                for (int j = 0; j < 4; ++j) {
                    float4 v = h4[(size_t)s * 64 + j * 16 + q];
                    int jj = (j * 16 + q) ^ sw;      // swizzled float4 col
                    float* p = shf + ((r * 64 + jj) << 2);
                    atomicAdd(p + 0, v.x);
                    atomicAdd(p + 1, v.y);
                    atomicAdd(p + 2, v.z);
                    atomicAdd(p + 3, v.w);
                }
            }
        }
        __syncthreads();
        // ---- split-bf16 MFMA GEMM: acc += Sh @ W[t][:, 64w..64w+64)
        const short* WH = Whi + ((size_t)t << 16);
        const short* WL = Wlo + ((size_t)t << 16);
        #pragma unroll 2
        for (int K0 = 0; K0 < 8; ++K0) {             // K = K0*32
            bf16x8 bh[4], bl[4];
            #pragma unroll
            for (int cb = 0; cb < 4; ++cb) {
                int col = (w << 6) + (cb << 4) + ln15;
                size_t off = (size_t)col * 256 + (K0 << 5) + (lhi << 3);
                bh[cb] = *reinterpret_cast<const bf16x8*>(WH + off);
                bl[cb] = *reinterpret_cast<const bf16x8*>(WL + off);
            }
            #pragma unroll
            for (int rf = 0; rf < 2; ++rf) {
                int row = (rf << 4) + ln15;
                int j0  = (K0 << 3) + (lhi << 1);
                int sw  = row & 7;
                float4 a0 = Sh4[row * 64 + (j0 ^ sw)];
                float4 a1 = Sh4[row * 64 + ((j0 + 1) ^ sw)];
                bf16x8 ah, al;
                split8(a0, a1, ah, al);
                #pragma unroll
                for (int cb = 0; cb < 4; ++cb) {
                    acc[rf][cb] = __builtin_amdgcn_mfma_f32_16x16x32_bf16(ah, bh[cb], acc[rf][cb], 0, 0, 0);
                    acc[rf][cb] = __builtin_amdgcn_mfma_f32_16x16x32_bf16(ah, bl[cb], acc[rf][cb], 0, 0, 0);
                    acc[rf][cb] = __builtin_amdgcn_mfma_f32_16x16x32_bf16(al, bh[cb], acc[rf][cb], 0, 0, 0);
                }
            }
        }
        __syncthreads();                             // Sh reused next etype
    }
    // ---- C write: C/D layout col=lane&15, row=(lane>>4)*4+reg
    #pragma unroll
    for (int rf = 0; rf < 2; ++rf) {
        #pragma unroll
        for (int m = 0; m < 4; ++m) {
            int row = br + (rf << 4) + (lhi << 2) + m;
            if (row < N_NODES) {
                #pragma unroll
                for (int cb = 0; cb < 4; ++cb) {
                    int col = (w << 6) + (cb << 4) + ln15;
                    a[(size_t)row * 256 + col] = acc[rf][cb][m];
                }
            }
        }
    }
}

// ---------------- MFMA GRU kernel ----------------
// Block = 64 rows x 64 f-cols; wave w owns rows [16w,16w+16).
// Per wave: 6 gate-tiles (xr,xz,xn,hr,hz,hn) of 16x64, K=256, split-bf16
// MFMA (3 products). A-frags loaded per-lane from global (L2/L3-resident),
// B-frags from pre-split W_ih/W_hh (nn.Linear rows are already [n][k]).
__device__ __forceinline__ float sigm(float x) { return 1.0f / (1.0f + expf(-x)); }

__global__ __launch_bounds__(256, 2) void k_gru(const float* __restrict__ a,
                                                const float* __restrict__ h,
                                                const short* __restrict__ WihH,
                                                const short* __restrict__ WihL,
                                                const short* __restrict__ WhhH,
                                                const short* __restrict__ WhhL,
                                                const float* __restrict__ b_ih,
                                                const float* __restrict__ b_hh,
                                                float* __restrict__ hN) {
    const int br   = blockIdx.x * 64;
    const int f0   = blockIdx.y * 64;
    const int tid  = threadIdx.x;
    const int w    = tid >> 6;
    const int l    = tid & 63;
    const int ln15 = l & 15;
    const int lhi  = l >> 4;

    f32x4 accx[3][4] = {};                           // [gate][col-frag]
    f32x4 acch[3][4] = {};

    int rowA = br + (w << 4) + ln15;                 // A-frag row for this lane
    if (rowA >= N_NODES) rowA = N_NODES - 1;         // clamp, stores guarded
    const float* aRow = a + (size_t)rowA * 256;
    const float* hRow = h + (size_t)rowA * 256;

    #pragma unroll 2
    for (int K0 = 0; K0 < 8; ++K0) {
        const int koff = (K0 << 5) + (lhi << 3);
        float4 av0 = *(const float4*)(aRow + koff);
        float4 av1 = *(const float4*)(aRow + koff + 4);
        float4 hv0 = *(const float4*)(hRow + koff);
        float4 hv1 = *(const float4*)(hRow + koff + 4);
        bf16x8 aH, aL, hH, hL;
        split8(av0, av1, aH, aL);
        split8(hv0, hv1, hH, hL);
        #pragma unroll
        for (int g = 0; g < 3; ++g) {
            #pragma unroll
            for (int cb = 0; cb < 4; ++cb) {
                int col = g * 256 + f0 + (cb << 4) + ln15;
                size_t off = (size_t)col * 256 + koff;
                bf16x8 bH = *reinterpret_cast<const bf16x8*>(WihH + off);
                bf16x8 bL = *reinterpret_cast<const bf16x8*>(WihL + off);
                accx[g][cb] = __builtin_amdgcn_mfma_f32_16x16x32_bf16(aH, bH, accx[g][cb], 0, 0, 0);
                accx[g][cb] = __builtin_amdgcn_mfma_f32_16x16x32_bf16(aH, bL, accx[g][cb], 0, 0, 0);
                accx[g][cb] = __builtin_amdgcn_mfma_f32_16x16x32_bf16(aL, bH, accx[g][cb], 0, 0, 0);
                bH = *reinterpret_cast<const bf16x8*>(WhhH + off);
                bL = *reinterpret_cast<const bf16x8*>(WhhL + off);
                acch[g][cb] = __builtin_amdgcn_mfma_f32_16x16x32_bf16(hH, bH, acch[g][cb], 0, 0, 0);
                acch[g][cb] = __builtin_amdgcn_mfma_f32_16x16x32_bf16(hH, bL, acch[g][cb], 0, 0, 0);
                acch[g][cb] = __builtin_amdgcn_mfma_f32_16x16x32_bf16(hL, bH, acch[g][cb], 0, 0, 0);
            }
        }
    }
    // ---- gate epilogue; C/D frag: col = 16cb+ln15, row = 16w + 4*lhi + m
    #pragma unroll
    for (int cb = 0; cb < 4; ++cb) {
        int f = f0 + (cb << 4) + ln15;
        float bxr = b_ih[f], bxz = b_ih[256 + f], bxn = b_ih[512 + f];
        float bhr = b_hh[f], bhz = b_hh[256 + f], bhn = b_hh[512 + f];
        #pragma unroll
        for (int m = 0; m < 4; ++m) {
            int row = br + (w << 4) + (lhi << 2) + m;
            if (row >= N_NODES) continue;
            float hv = h[(size_t)row * 256 + f];
            float r = sigm(accx[0][cb][m] + bxr + acch[0][cb][m] + bhr);
            float z = sigm(accx[1][cb][m] + bxz + acch[1][cb][m] + bhz);
            float n = tanhf(accx[2][cb][m] + bxn + r * (acch[2][cb][m] + bhn));
            hN[(size_t)row * 256 + f] = (1.f - z) * n + z * hv;
        }
    }
}

// ---------------- readout ----------------
__global__ __launch_bounds__(256) void k_readout1(const float* __restrict__ h,
                                                  const int* __restrict__ gid,
                                                  float* __restrict__ hg) {
    int row0 = blockIdx.x * 32;
    if (row0 >= N_NODES) return;
    int f = threadIdx.x;
    int end = row0 + 32; if (end > N_NODES) end = N_NODES;
    float acc = 0.f;
    int cur = gid[row0];
    for (int r = row0; r < end; ++r) {
        int g = gid[r];
        if (g != cur) {
            atomicAdd(&hg[cur * HIDDEN + f], acc);
            acc = 0.f; cur = g;
        }
        float x = h[(size_t)r * HIDDEN + f];
        acc += (x > 0.f) ? x : 0.f;
    }
    atomicAdd(&hg[cur * HIDDEN + f], acc);
}

__global__ __launch_bounds__(256) void k_readout2(const float* __restrict__ hg,
                                                  const float* __restrict__ Wc,
                                                  const float* __restrict__ bc,
                                                  float* __restrict__ out) {
    __shared__ float s[256];
    int g = blockIdx.x;
    int f = threadIdx.x;
    s[f] = hg[g * HIDDEN + f] * Wc[f];
    __syncthreads();
    for (int off = 128; off > 0; off >>= 1) {
        if (f < off) s[f] += s[f + off];
        __syncthreads();
    }
    if (f == 0) out[g] = 1.0f / (1.0f + expf(-(s[0] + bc[0])));
}

// ---------------- launch ----------------
extern "C" void kernel_launch(void* const* d_in, const int* in_sizes, int n_in,
                              void* d_out, int out_size, void* d_ws, size_t ws_size,
                              hipStream_t stream) {
    const float* feat  = (const float*)d_in[0];
    const float* W     = (const float*)d_in[1];
    const float* W_ih  = (const float*)d_in[2];
    const float* W_hh  = (const float*)d_in[3];
    const float* b_ih  = (const float*)d_in[4];
    const float* b_hh  = (const float*)d_in[5];
    const float* Wc    = (const float*)d_in[6];
    const float* bc    = (const float*)d_in[7];
    const int*   src   = (const int*)d_in[8];
    const int*   dst   = (const int*)d_in[9];
    const int*   etype = (const int*)d_in[10];
    const int*   gid   = (const int*)d_in[11];
    float* out = (float*)d_out;

    char* ws = (char*)d_ws;
    size_t off = 0;
    auto alloc = [&](size_t bytes) {
        void* p = ws + off;
        off += (bytes + 255) & ~(size_t)255;
        return p;
    };
    // total ~168 MB
    float* hA   = (float*)alloc((size_t)N_NODES * HIDDEN * 4);   // 51.2 MB
    float* hB   = (float*)alloc((size_t)N_NODES * HIDDEN * 4);   // 51.2 MB
    float* a    = (float*)alloc((size_t)N_NODES * HIDDEN * 4);   // 51.2 MB
    int* bufA   = (int*)alloc((size_t)(NKEYS + 1) * 4);          // counts, then ptr
    int* bufB   = (int*)alloc((size_t)NKEYS * 4);                // lexcl, then cursor
    unsigned* ebuf = (unsigned*)alloc((size_t)N_EDGES * 4);      // (dst<<16)|src
    int* bsums  = (int*)alloc((size_t)2048 * 4);
    float* hg   = (float*)alloc((size_t)NUM_GRAPHS * HIDDEN * 4);
    short* Whi  = (short*)alloc((size_t)N_ETYPES * 65536 * 2);   // 1.7 MB
    short* Wlo  = (short*)alloc((size_t)N_ETYPES * 65536 * 2);   // 1.7 MB
    short* WihH = (short*)alloc((size_t)768 * 256 * 2);          // 393 KB
    short* WihL = (short*)alloc((size_t)768 * 256 * 2);
    short* WhhH = (short*)alloc((size_t)768 * 256 * 2);
    short* WhhL = (short*)alloc((size_t)768 * 256 * 2);
    (void)ws_size; (void)n_in; (void)in_sizes; (void)out_size;

    const int SCAN_BLOCKS = (NKEYS + SCAN_T - 1) / SCAN_T;       // 1270
    const int NLIN = 768 * 256;

    // ---- CSR build, bucketed by (etype, dst) ----
    hipMemsetAsync(bufA, 0, (size_t)NKEYS * 4, stream);
    k_hist<<<(N_EDGES + 255) / 256, 256, 0, stream>>>(dst, etype, bufA);
    k_scan1<<<SCAN_BLOCKS, SCAN_T, 0, stream>>>(bufA, bufB, bsums, NKEYS);
    k_scan2<<<1, 256, 0, stream>>>(bsums, SCAN_BLOCKS, bufA);
    k_scan3<<<SCAN_BLOCKS, SCAN_T, 0, stream>>>(bufB, bsums, bufA, NKEYS);
    hipMemcpyAsync(bufB, bufA, (size_t)NKEYS * 4, hipMemcpyDeviceToDevice, stream);
    k_place<<<(N_EDGES + 255) / 256, 256, 0, stream>>>(dst, etype, src, bufB, ebuf);

    // ---- weight splits (once) + h0 ----
    k_splitW<<<(N_ETYPES * 65536 + 255) / 256, 256, 0, stream>>>(W, Whi, Wlo);
    k_splitLin<<<(NLIN + 255) / 256, 256, 0, stream>>>(W_ih, WihH, WihL, NLIN);
    k_splitLin<<<(NLIN + 255) / 256, 256, 0, stream>>>(W_hh, WhhH, WhhL, NLIN);
    k_init_h<<<(N_NODES * 64 + 255) / 256, 256, 0, stream>>>(feat, hA);

    float* hc = hA;
    float* hn = hB;
    const dim3 gMsg((N_NODES + 31) / 32, 1);                     // 1563
    const dim3 gGru((N_NODES + 63) / 64, HIDDEN / 64);           // 782 x 4

    for (int step = 0; step < N_STEPS; ++step) {
        k_msg<<<gMsg, 256, 0, stream>>>(ebuf, bufA, hc, Whi, Wlo, a);
        k_gru<<<gGru, 256, 0, stream>>>(a, hc, WihH, WihL, WhhH, WhhL,
                                        b_ih, b_hh, hn);
        float* tmp = hc; hc = hn; hn = tmp;
    }

    // ---- readout ----
    hipMemsetAsync(hg, 0, (size_t)NUM_GRAPHS * HIDDEN * 4, stream);
    k_readout1<<<(N_NODES + 31) / 32, 256, 0, stream>>>(hc, gid, hg);
    k_readout2<<<NUM_GRAPHS, 256, 0, stream>>>(hg, Wc, bc, out);
}